// Round 1
// baseline (116.808 us; speedup 1.0000x reference)
//
#include <hip/hip_runtime.h>

// Problem constants (from setup_inputs): B=4, Nc=1024, Nf=8192, fp32.
#define B  4
#define NF 8192
#define NC 1024

// Chamfer tiling: 256 threads/block, each thread owns 4 x-points (XC=1024),
// y staged in LDS in chunks of YC=1024 points as float4 (y0,y1,y2,|y|^2).
#define XC 1024
#define YC 1024
#define NXC (NF / XC)   // 8
#define NYC (NF / YC)   // 8

#define NMIN (2 * B * NF)   // 65536 per-point NN-min slots (both directions)
#define NCRS (B * NC)       // 4096 coarse points
#define NTOT (NMIN + NCRS)

// ---------------------------------------------------------------------------
// ws layout:  [0, NMIN) uint  : per-point min sqdist (bit pattern, >=0 floats)
//             [NMIN, +3) float: accumulators {coarse_sum, d1_sum, d2_sum}
// ws is poisoned 0xAA before every launch -> must init everything ourselves.
// ---------------------------------------------------------------------------

__global__ __launch_bounds__(256) void k_init(unsigned* __restrict__ minbuf,
                                              float* __restrict__ acc) {
    int i = blockIdx.x * 256 + threadIdx.x;
    if (i < NMIN) minbuf[i] = 0x7F800000u;  // +inf
    if (i < 3)    acc[i] = 0.0f;
}

// dir 0: x = ret_fine, y = gt_fine  (d1: each ret point -> nearest gt)
// dir 1: x = gt_fine,  y = ret_fine (d2: each gt point -> nearest ret)
__global__ __launch_bounds__(256) void k_chamfer(const float* __restrict__ rf,
                                                 const float* __restrict__ gf,
                                                 unsigned* __restrict__ minbuf) {
    __shared__ float4 ys[YC];   // 16 KB

    int bx   = blockIdx.x;          // 512 blocks total
    int dir  = bx >> 8;             // 256 blocks per direction
    int rem  = bx & 255;
    int b    = rem >> 6;            // 64 blocks per batch
    int rem2 = rem & 63;
    int xi   = rem2 >> 3;           // 8 x-chunks
    int yj   = rem2 & 7;            // 8 y-chunks

    const float* xp = dir ? gf : rf;
    const float* yp = dir ? rf : gf;
    int t = threadIdx.x;

    // Stage y chunk -> LDS float4 (y0, y1, y2, |y|^2)
    const float* yb = yp + (size_t)(b * NF + yj * YC) * 3;
    for (int j = t; j < YC; j += 256) {
        float y0 = yb[3 * j + 0], y1 = yb[3 * j + 1], y2 = yb[3 * j + 2];
        ys[j] = make_float4(y0, y1, y2, fmaf(y0, y0, fmaf(y1, y1, y2 * y2)));
    }

    // Per-thread x points: precompute m = -2x and c = |x|^2
    const float* xb = xp + (size_t)(b * NF + xi * XC) * 3;
    float m0[4], m1[4], m2[4], cc[4], mn[4];
#pragma unroll
    for (int k = 0; k < 4; ++k) {
        int i = k * 256 + t;
        float x0 = xb[3 * i + 0], x1 = xb[3 * i + 1], x2 = xb[3 * i + 2];
        m0[k] = -2.0f * x0;
        m1[k] = -2.0f * x1;
        m2[k] = -2.0f * x2;
        cc[k] = fmaf(x0, x0, fmaf(x1, x1, x2 * x2));
        mn[k] = 3.0e38f;
    }
    __syncthreads();

    // Hot loop: 1 broadcast ds_read_b128 + 4 x (3 fma + 1 add + 1 min)
#pragma unroll 4
    for (int j = 0; j < YC; ++j) {
        float4 y = ys[j];
#pragma unroll
        for (int k = 0; k < 4; ++k) {
            float d = fmaf(m2[k], y.z, fmaf(m1[k], y.y, fmaf(m0[k], y.x, cc[k]))) + y.w;
            mn[k] = fminf(mn[k], d);
        }
    }

    // Combine partial mins across y-chunks: uint atomicMin is order-correct
    // for non-negative IEEE floats (we clamp the tiny negative cancellation).
    unsigned* mb = minbuf + dir * (B * NF) + b * NF + xi * XC;
#pragma unroll
    for (int k = 0; k < 4; ++k) {
        float v = fmaxf(mn[k], 0.0f);
        atomicMin(&mb[k * 256 + t], __float_as_uint(v));
    }
}

__global__ __launch_bounds__(256) void k_reduce(const unsigned* __restrict__ minbuf,
                                                const float* __restrict__ rc,
                                                const float* __restrict__ gc,
                                                float* __restrict__ acc) {
    float s0 = 0.f, s1 = 0.f, s2 = 0.f;  // coarse, d1, d2
    for (int i = blockIdx.x * 256 + threadIdx.x; i < NTOT; i += gridDim.x * 256) {
        if (i < NMIN) {
            float v = sqrtf(__uint_as_float(minbuf[i]));
            if (i < B * NF) s1 += v; else s2 += v;
        } else {
            int p = i - NMIN;
            float dx = rc[3 * p + 0] - gc[3 * p + 0];
            float dy = rc[3 * p + 1] - gc[3 * p + 1];
            float dz = rc[3 * p + 2] - gc[3 * p + 2];
            s0 += sqrtf(fmaf(dx, dx, fmaf(dy, dy, dz * dz)));
        }
    }
    // wave64 shuffle reduction
#pragma unroll
    for (int off = 32; off > 0; off >>= 1) {
        s0 += __shfl_down(s0, off);
        s1 += __shfl_down(s1, off);
        s2 += __shfl_down(s2, off);
    }
    __shared__ float red[3][4];
    int lane = threadIdx.x & 63, w = threadIdx.x >> 6;
    if (lane == 0) { red[0][w] = s0; red[1][w] = s1; red[2][w] = s2; }
    __syncthreads();
    if (threadIdx.x == 0) {
        float t0 = 0.f, t1 = 0.f, t2 = 0.f;
        for (int ww = 0; ww < 4; ++ww) { t0 += red[0][ww]; t1 += red[1][ww]; t2 += red[2][ww]; }
        atomicAdd(&acc[0], t0);
        atomicAdd(&acc[1], t1);
        atomicAdd(&acc[2], t2);
    }
}

__global__ void k_final(const float* __restrict__ acc, float* __restrict__ out) {
    if (threadIdx.x == 0) {
        out[0] = acc[0] * (1.0f / (float)NCRS);                       // loss_coarse
        out[1] = 0.5f * (acc[1] + acc[2]) * (1.0f / (float)(B * NF)); // loss_fine
    }
}

extern "C" void kernel_launch(void* const* d_in, const int* in_sizes, int n_in,
                              void* d_out, int out_size, void* d_ws, size_t ws_size,
                              hipStream_t stream) {
    const float* rc = (const float*)d_in[0];  // ret_coarse [4,1024,3]
    const float* rf = (const float*)d_in[1];  // ret_fine   [4,8192,3]
    const float* gf = (const float*)d_in[2];  // gt_fine    [4,8192,3]
    const float* gc = (const float*)d_in[3];  // gt_coarse  [4,1024,3]

    unsigned* minbuf = (unsigned*)d_ws;
    float*    acc    = (float*)((char*)d_ws + (size_t)NMIN * sizeof(unsigned));
    float*    out    = (float*)d_out;

    k_init<<<NMIN / 256, 256, 0, stream>>>(minbuf, acc);
    k_chamfer<<<2 * B * NXC * NYC, 256, 0, stream>>>(rf, gf, minbuf);
    k_reduce<<<128, 256, 0, stream>>>(minbuf, rc, gc, acc);
    k_final<<<1, 64, 0, stream>>>(acc, out);
}

// Round 2
// 111.924 us; speedup vs baseline: 1.0436x; 1.0436x over previous
//
#include <hip/hip_runtime.h>

// Problem constants (from setup_inputs): B=4, Nc=1024, Nf=8192, fp32.
#define B  4
#define NF 8192
#define NC 1024

// Chamfer tiling: 256 threads/block, K=16 x-points per thread (XC=4096),
// y staged in LDS in chunks of YC=128 points as float4 (y0,y1,y2,|y|^2).
// 80 VALU ops per ds_read_b128 -> LDS pipe ~10us << VALU ~31us.
#define K  16
#define XC (K * 256)    // 4096
#define NXC (NF / XC)   // 2
#define YC 128
#define NYC (NF / YC)   // 64

#define NMIN (2 * B * NF)   // 65536 per-point NN-min slots (both directions)
#define NCRS (B * NC)       // 4096 coarse points
#define NTOT (NMIN + NCRS)

// ---------------------------------------------------------------------------
// ws layout: [0, NMIN) uint : per-point min sqdist bit pattern.
// Initialized to 0xFFFFFFFF (uint max) via hipMemsetAsync -> atomicMin works
// without an init kernel. d_out zeroed via 8-byte memset; reduce blocks
// atomicAdd pre-scaled partials straight into d_out (no finalize kernel).
// ---------------------------------------------------------------------------

// dir 0: x = ret_fine, y = gt_fine  (d1: each ret point -> nearest gt)
// dir 1: x = gt_fine,  y = ret_fine (d2: each gt point -> nearest ret)
__global__ __launch_bounds__(256) void k_chamfer(const float* __restrict__ rf,
                                                 const float* __restrict__ gf,
                                                 unsigned* __restrict__ minbuf) {
    __shared__ float4 ys[YC];   // 2 KB

    int bx   = blockIdx.x;          // 1024 blocks total
    int dir  = bx >> 9;             // 512 blocks per direction
    int rem  = bx & 511;
    int b    = rem >> 7;            // 128 blocks per batch
    int rem2 = rem & 127;
    int xi   = rem2 >> 6;           // 2 x-chunks
    int yj   = rem2 & 63;           // 64 y-chunks

    const float* xp = dir ? gf : rf;
    const float* yp = dir ? rf : gf;
    int t = threadIdx.x;

    // Stage y chunk -> LDS float4 (y0, y1, y2, |y|^2)
    const float* yb = yp + (size_t)(b * NF + yj * YC) * 3;
    if (t < YC) {
        float y0 = yb[3 * t + 0], y1 = yb[3 * t + 1], y2 = yb[3 * t + 2];
        ys[t] = make_float4(y0, y1, y2, fmaf(y0, y0, fmaf(y1, y1, y2 * y2)));
    }

    // Per-thread x points: precompute m = -2x and c = |x|^2
    const float* xb = xp + (size_t)(b * NF + xi * XC) * 3;
    float m0[K], m1[K], m2[K], cc[K], mn[K];
#pragma unroll
    for (int k = 0; k < K; ++k) {
        int i = k * 256 + t;
        float x0 = xb[3 * i + 0], x1 = xb[3 * i + 1], x2 = xb[3 * i + 2];
        m0[k] = -2.0f * x0;
        m1[k] = -2.0f * x1;
        m2[k] = -2.0f * x2;
        cc[k] = fmaf(x0, x0, fmaf(x1, x1, x2 * x2));
        mn[k] = 3.4e38f;
    }
    __syncthreads();

    // Hot loop: 2 broadcast ds_read_b128 + K x (6 fma + 2 add + 1 min3)
    // = 4.5 VALU ops per pair evaluation.
#pragma unroll 2
    for (int j = 0; j < YC; j += 2) {
        float4 ya = ys[j];
        float4 yb4 = ys[j + 1];
#pragma unroll
        for (int k = 0; k < K; ++k) {
            float da = fmaf(m2[k], ya.z,  fmaf(m1[k], ya.y,  fmaf(m0[k], ya.x,  cc[k]))) + ya.w;
            float db = fmaf(m2[k], yb4.z, fmaf(m1[k], yb4.y, fmaf(m0[k], yb4.x, cc[k]))) + yb4.w;
            mn[k] = fminf(fminf(da, db), mn[k]);   // -> v_min3_f32
        }
    }

    // Combine partial mins across y-chunks: uint atomicMin is order-correct
    // for non-negative IEEE floats (clamp the tiny negative cancellation).
    unsigned* mb = minbuf + dir * (B * NF) + b * NF + xi * XC;
#pragma unroll
    for (int k = 0; k < K; ++k) {
        float v = fmaxf(mn[k], 0.0f);
        atomicMin(&mb[k * 256 + t], __float_as_uint(v));
    }
}

__global__ __launch_bounds__(256) void k_reduce(const unsigned* __restrict__ minbuf,
                                                const float* __restrict__ rc,
                                                const float* __restrict__ gc,
                                                float* __restrict__ out) {
    float s_crs = 0.f, s_fine = 0.f;
    for (int i = blockIdx.x * 256 + threadIdx.x; i < NTOT; i += gridDim.x * 256) {
        if (i < NMIN) {
            s_fine += sqrtf(__uint_as_float(minbuf[i]));
        } else {
            int p = i - NMIN;
            float dx = rc[3 * p + 0] - gc[3 * p + 0];
            float dy = rc[3 * p + 1] - gc[3 * p + 1];
            float dz = rc[3 * p + 2] - gc[3 * p + 2];
            s_crs += sqrtf(fmaf(dx, dx, fmaf(dy, dy, dz * dz)));
        }
    }
    // wave64 shuffle reduction
#pragma unroll
    for (int off = 32; off > 0; off >>= 1) {
        s_crs  += __shfl_down(s_crs, off);
        s_fine += __shfl_down(s_fine, off);
    }
    __shared__ float red[2][4];
    int lane = threadIdx.x & 63, w = threadIdx.x >> 6;
    if (lane == 0) { red[0][w] = s_crs; red[1][w] = s_fine; }
    __syncthreads();
    if (threadIdx.x == 0) {
        float t0 = red[0][0] + red[0][1] + red[0][2] + red[0][3];
        float t1 = red[1][0] + red[1][1] + red[1][2] + red[1][3];
        atomicAdd(&out[0], t0 * (1.0f / (float)NCRS));                 // loss_coarse
        atomicAdd(&out[1], t1 * (0.5f / (float)(B * NF)));             // loss_fine
    }
}

extern "C" void kernel_launch(void* const* d_in, const int* in_sizes, int n_in,
                              void* d_out, int out_size, void* d_ws, size_t ws_size,
                              hipStream_t stream) {
    const float* rc = (const float*)d_in[0];  // ret_coarse [4,1024,3]
    const float* rf = (const float*)d_in[1];  // ret_fine   [4,8192,3]
    const float* gf = (const float*)d_in[2];  // gt_fine    [4,8192,3]
    const float* gc = (const float*)d_in[3];  // gt_coarse  [4,1024,3]

    unsigned* minbuf = (unsigned*)d_ws;
    float*    out    = (float*)d_out;

    // 0xFFFFFFFF = uint max -> atomicMin sentinel; memset nodes are
    // graph-capturable (the harness itself uses hipMemsetAsync).
    hipMemsetAsync(minbuf, 0xFF, (size_t)NMIN * sizeof(unsigned), stream);
    hipMemsetAsync(out, 0, 2 * sizeof(float), stream);

    k_chamfer<<<2 * B * NXC * NYC, 256, 0, stream>>>(rf, gf, minbuf);
    k_reduce<<<64, 256, 0, stream>>>(minbuf, rc, gc, out);
}